// Round 3
// baseline (199.639 us; speedup 1.0000x reference)
//
#include <hip/hip_runtime.h>

// BioNorm: out = w * x^p / (sigma^p + depthwise_conv5x5(x^p, edge-pad)) + b
// B=32, C=64, H=W=112, K=5, fp32.
//
// V4: 256-thr blocks (2 channels/block) + box-filter fast path.
//  R2 post-mortem: removing LDS did NOT raise occupancy (35% both R1/R2 with
//  128-thr blocks vs 72% in R0 with 256-thr) -> residency is per-workgroup-
//  slot limited (~5.6 blocks/CU across all three rounds), so block size sets
//  resident waves. Kernel is latency-bound (VALU 32%, HBM 30%, both low).
//  - 256 threads = 2 channels x 4 strips x 32 lanes; channel = tid>>7 is
//    wave-uniform (waves 0,1 -> c0; waves 2,3 -> c1). No LDS, no barriers.
//  - Fast path (runtime per-channel check, wave-uniform branch): if all 25
//    taps equal, conv = k0 * boxsum. Rolling vertical column-sums v[8]
//    (+new/-old row, 16 adds) + incremental horizontal box (10 adds) replace
//    the 100-FMA window: ~50 vs ~139 VALU ops per row. General path kept.
//  - Same center-anchored sliding 5x8 register window as R2: lane g owns
//    center cols [4g+2,4g+5]; two 16B dwordx4 loads per new row, prefetch
//    depth 1; edge-padded outputs reuse clamped-center denominators.

#define Cch 64
#define Hh 112
#define Ww 112
#define CPB 36            // center rows per block-x (grid.x = 3)
#define RPS 9             // center rows per strip (4 strips per channel)

__global__ __launch_bounds__(256) void bionorm_kernel(
    const float* __restrict__ x, const float* __restrict__ sigma,
    const float* __restrict__ pow_p, const float* __restrict__ sum_kernel,
    const float* __restrict__ weight, const float* __restrict__ bias,
    float* __restrict__ out)
{
    const int bx  = blockIdx.x;                       // 0..2 (center-row tile)
    const int b   = blockIdx.z;
    const int tid = threadIdx.x;
    const int c   = blockIdx.y * 2 + (tid >> 7);      // wave-uniform channel
    const int t   = tid & 127;

    const int ss = t >> 5;        // strip 0..3
    const int g  = t & 31;        // column group; 27 active
    if (g >= 27) return;

    // per-channel params (wave-uniform)
    const float p  = pow_p[c];
    const float sg = sigma[c];
    const float wc = weight[c];
    const float bc = bias[c];
    const bool  p2 = (p == 2.0f);
    const float sp = p2 ? sg * sg : __powf(sg, p);

    float kw[25];
    const float* kp = sum_kernel + c * 25;
    #pragma unroll
    for (int j = 0; j < 25; ++j) kw[j] = kp[j];
    bool uni = true;
    #pragma unroll
    for (int j = 1; j < 25; ++j) uni = uni && (kw[j] == kw[0]);

    const float* xplane = x + ((size_t)(b * Cch + c)) * (Hh * Ww);
    float* oplane = out + ((size_t)(b * Cch + c)) * (Hh * Ww);

    const int cs   = 2 + bx * CPB + ss * RPS;  // first center row of this strip
    const int col0 = 4 * g;                    // window col base

    // sliding window: win[(r-(cs-2)) % 5] holds x^p of global row r, cols [col0,col0+8)
    float win[5][8];

    #define CVT8(SL, VA, VB) { \
        if (p2) { \
            win[SL][0] = VA.x * VA.x; win[SL][1] = VA.y * VA.y; \
            win[SL][2] = VA.z * VA.z; win[SL][3] = VA.w * VA.w; \
            win[SL][4] = VB.x * VB.x; win[SL][5] = VB.y * VB.y; \
            win[SL][6] = VB.z * VB.z; win[SL][7] = VB.w * VB.w; \
        } else { \
            win[SL][0] = __powf(VA.x, p); win[SL][1] = __powf(VA.y, p); \
            win[SL][2] = __powf(VA.z, p); win[SL][3] = __powf(VA.w, p); \
            win[SL][4] = __powf(VB.x, p); win[SL][5] = __powf(VB.y, p); \
            win[SL][6] = __powf(VB.z, p); win[SL][7] = __powf(VB.w, p); \
        } }

    // emit one output row GR: numerator from window slot SL, denominators d0..d3
    #define EMITROW(GR, SL) { \
        float* orw_ = oplane + (GR) * Ww; \
        *(float2*)(orw_ + col0 + 2) = make_float2(fmaf(wc * win[SL][2], d0, bc), \
                                                  fmaf(wc * win[SL][3], d1, bc)); \
        *(float2*)(orw_ + col0 + 4) = make_float2(fmaf(wc * win[SL][4], d2, bc), \
                                                  fmaf(wc * win[SL][5], d3, bc)); \
        if (g == 0)  *(float2*)(orw_)       = make_float2(fmaf(wc * win[SL][0], d0, bc), \
                                                          fmaf(wc * win[SL][1], d0, bc)); \
        if (g == 26) *(float2*)(orw_ + 110) = make_float2(fmaf(wc * win[SL][6], d3, bc), \
                                                          fmaf(wc * win[SL][7], d3, bc)); }

    #define EDGEEMITS() { \
        const int cgl = cs + k; \
        EMITROW(cgl, (k + 2) % 5) \
        if (k == 0 && cs == 2) {           /* replicate-pad rows 0,1 */ \
            EMITROW(0, 0) \
            EMITROW(1, 1) \
        } \
        if (k == RPS - 1 && cgl == 109) {  /* replicate-pad rows 110,111 */ \
            EMITROW(110, (k + 3) % 5) \
            EMITROW(111, (k + 4) % 5) \
        } }

    // ---- prologue: rows cs-2 .. cs+1 -> slots 0..3; prefetch row cs+2 ----
    {
        const float4 a0 = *(const float4*)(xplane + (cs - 2) * Ww + col0);
        const float4 b0 = *(const float4*)(xplane + (cs - 2) * Ww + col0 + 4);
        const float4 a1 = *(const float4*)(xplane + (cs - 1) * Ww + col0);
        const float4 b1 = *(const float4*)(xplane + (cs - 1) * Ww + col0 + 4);
        const float4 a2 = *(const float4*)(xplane + (cs    ) * Ww + col0);
        const float4 b2 = *(const float4*)(xplane + (cs    ) * Ww + col0 + 4);
        const float4 a3 = *(const float4*)(xplane + (cs + 1) * Ww + col0);
        const float4 b3 = *(const float4*)(xplane + (cs + 1) * Ww + col0 + 4);
        CVT8(0, a0, b0) CVT8(1, a1, b1) CVT8(2, a2, b2) CVT8(3, a3, b3)
    }
    float4 A0 = *(const float4*)(xplane + (cs + 2) * Ww + col0);
    float4 A1 = *(const float4*)(xplane + (cs + 2) * Ww + col0 + 4);

    if (uni) {
        // ---- box-filter fast path: conv = kw[0] * boxsum ----
        const float k0 = kw[0];
        float v[8];   // running vertical column sums over the 5-row window
        #pragma unroll
        for (int tt = 0; tt < 8; ++tt)
            v[tt] = win[0][tt] + win[1][tt] + win[2][tt] + win[3][tt];

        #pragma unroll
        for (int k = 0; k < RPS; ++k) {
            const int nr  = cs + k + 3;
            const int nrc = nr > 111 ? 111 : nr;
            const float4 B0 = *(const float4*)(xplane + nrc * Ww + col0);
            const float4 B1 = *(const float4*)(xplane + nrc * Ww + col0 + 4);

            const int sl = (k + 4) % 5;
            CVT8(sl, A0, A1)
            #pragma unroll
            for (int tt = 0; tt < 8; ++tt) v[tt] += win[sl][tt];

            const float h0 = ((v[0] + v[1]) + (v[2] + v[3])) + v[4];
            const float h1 = h0 - v[0] + v[5];
            const float h2 = h1 - v[1] + v[6];
            const float h3 = h2 - v[2] + v[7];

            const float d0 = __builtin_amdgcn_rcpf(fmaf(k0, h0, sp));
            const float d1 = __builtin_amdgcn_rcpf(fmaf(k0, h1, sp));
            const float d2 = __builtin_amdgcn_rcpf(fmaf(k0, h2, sp));
            const float d3 = __builtin_amdgcn_rcpf(fmaf(k0, h3, sp));

            EDGEEMITS()

            if (k < RPS - 1) {   // drop leaving row (slot k%5 = row cs+k-2)
                #pragma unroll
                for (int tt = 0; tt < 8; ++tt) v[tt] -= win[k % 5][tt];
            }
            A0 = B0; A1 = B1;
        }
    } else {
        // ---- general 25-tap path ----
        #pragma unroll
        for (int k = 0; k < RPS; ++k) {
            const int nr  = cs + k + 3;
            const int nrc = nr > 111 ? 111 : nr;
            const float4 B0 = *(const float4*)(xplane + nrc * Ww + col0);
            const float4 B1 = *(const float4*)(xplane + nrc * Ww + col0 + 4);

            CVT8((k + 4) % 5, A0, A1)

            float S0 = 0.f, S1 = 0.f, S2 = 0.f, S3 = 0.f;
            #pragma unroll
            for (int dy = 0; dy < 5; ++dy) {
                const int sl = (k + dy) % 5;
                #pragma unroll
                for (int dx = 0; dx < 5; ++dx) {
                    const float kv = kw[dy * 5 + dx];
                    S0 = fmaf(kv, win[sl][dx + 0], S0);
                    S1 = fmaf(kv, win[sl][dx + 1], S1);
                    S2 = fmaf(kv, win[sl][dx + 2], S2);
                    S3 = fmaf(kv, win[sl][dx + 3], S3);
                }
            }

            const float d0 = __builtin_amdgcn_rcpf(sp + S0);
            const float d1 = __builtin_amdgcn_rcpf(sp + S1);
            const float d2 = __builtin_amdgcn_rcpf(sp + S2);
            const float d3 = __builtin_amdgcn_rcpf(sp + S3);

            EDGEEMITS()

            A0 = B0; A1 = B1;
        }
    }
    #undef CVT8
    #undef EMITROW
    #undef EDGEEMITS
}

extern "C" void kernel_launch(void* const* d_in, const int* in_sizes, int n_in,
                              void* d_out, int out_size, void* d_ws, size_t ws_size,
                              hipStream_t stream) {
    const float* x          = (const float*)d_in[0];
    const float* sigma      = (const float*)d_in[1];
    const float* pow_p      = (const float*)d_in[2];
    const float* sum_kernel = (const float*)d_in[3];
    const float* weight     = (const float*)d_in[4];
    const float* bias       = (const float*)d_in[5];
    float* out = (float*)d_out;

    dim3 grid(3, Cch / 2, 32);   // (center-row tiles, channel pairs, B)
    dim3 block(256);
    bionorm_kernel<<<grid, block, 0, stream>>>(x, sigma, pow_p, sum_kernel,
                                               weight, bias, out);
}

// Round 5
// 195.727 us; speedup vs baseline: 1.0200x; 1.0200x over previous
//
#include <hip/hip_runtime.h>

// BioNorm: out = w * x^p / (sigma^p + depthwise_conv5x5(x^p, edge-pad)) + b
// B=32, C=64, H=W=112, K=5, fp32.
//
// V5b: batch-load MLP restructure (V5 with nontemporal-store type fix:
//  __builtin_nontemporal_store needs a NATIVE vector type, not HIP's
//  float2 struct -> use ext_vector_type(2)).
//  R3 post-mortem: occupancy pinned at ~35% regardless of block size/LDS;
//  waves stalled ~90% of residency on memory latency with only 2 loads in
//  flight (depth-1 prefetch). Both pipes idle (VALU 17%, HBM 31%).
//  - Each wave strip loads ALL 7 input rows (14 independent dwordx4 issued
//    back-to-back -> 14 outstanding loads/wave, 7x MLP), then computes
//    3 center rows entirely from registers. No sliding state, no LDS.
//  - Grid (9,32,32) = 9216 blocks (3x more) deepens residency pool.
//  - Non-temporal stores: output is write-once; nt keeps the 103MB input
//    L3-resident and frees HBM for writes.
//  - Box-filter fast path kept (runtime all-taps-equal check, wave-uniform).
//  - Lane g (0..26) owns center cols [4g+2,4g+5]; edge-padded outputs reuse
//    clamped-center denominators with real-pixel numerators. Loaded rows
//    rr0..rr0+6 with rr0 = bx*12+ss*3 in [0,105] -> never clamp.

#define Cch 64
#define Hh 112
#define Ww 112
#define RT 9              // row tiles (grid.x)
#define RPS 3             // center rows per strip

typedef float v2f __attribute__((ext_vector_type(2)));

__global__ __launch_bounds__(256) void bionorm_kernel(
    const float* __restrict__ x, const float* __restrict__ sigma,
    const float* __restrict__ pow_p, const float* __restrict__ sum_kernel,
    const float* __restrict__ weight, const float* __restrict__ bias,
    float* __restrict__ out)
{
    const int bx  = blockIdx.x;                   // 0..8 (center-row tile)
    const int b   = blockIdx.z;
    const int tid = threadIdx.x;
    const int c   = blockIdx.y * 2 + (tid >> 7);  // wave-uniform channel
    const int t   = tid & 127;
    const int ss  = t >> 5;                       // strip 0..3
    const int g   = t & 31;                       // column group; 27 active
    if (g >= 27) return;

    // per-channel params (wave-uniform)
    const float p  = pow_p[c];
    const float sg = sigma[c];
    const float wc = weight[c];
    const float bc = bias[c];
    const bool  p2 = (p == 2.0f);
    const float sp = p2 ? sg * sg : __powf(sg, p);

    float kw[25];
    const float* kp = sum_kernel + c * 25;
    #pragma unroll
    for (int j = 0; j < 25; ++j) kw[j] = kp[j];
    bool uni = true;
    #pragma unroll
    for (int j = 1; j < 25; ++j) uni = uni && (kw[j] == kw[0]);

    const float* xplane = x + ((size_t)(b * Cch + c)) * (Hh * Ww);
    float* oplane = out + ((size_t)(b * Cch + c)) * (Hh * Ww);

    const int cb   = 2 + bx * (4 * RPS) + ss * RPS; // first center row of strip
    const int rr0  = cb - 2;                        // first loaded row (in [0,105])
    const int col0 = 4 * g;                         // window col base

    // ---- issue all 14 loads back-to-back (MLP = 14) ----
    float4 ra[7], rb[7];
    #pragma unroll
    for (int i = 0; i < 7; ++i) {
        const float* rp = xplane + (rr0 + i) * Ww + col0;
        ra[i] = *(const float4*)(rp);
        rb[i] = *(const float4*)(rp + 4);
    }

    // ---- convert to x^p window: win[i] = row rr0+i, cols [col0, col0+8) ----
    float win[7][8];
    #pragma unroll
    for (int i = 0; i < 7; ++i) {
        if (p2) {
            win[i][0] = ra[i].x * ra[i].x; win[i][1] = ra[i].y * ra[i].y;
            win[i][2] = ra[i].z * ra[i].z; win[i][3] = ra[i].w * ra[i].w;
            win[i][4] = rb[i].x * rb[i].x; win[i][5] = rb[i].y * rb[i].y;
            win[i][6] = rb[i].z * rb[i].z; win[i][7] = rb[i].w * rb[i].w;
        } else {
            win[i][0] = __powf(ra[i].x, p); win[i][1] = __powf(ra[i].y, p);
            win[i][2] = __powf(ra[i].z, p); win[i][3] = __powf(ra[i].w, p);
            win[i][4] = __powf(rb[i].x, p); win[i][5] = __powf(rb[i].y, p);
            win[i][6] = __powf(rb[i].z, p); win[i][7] = __powf(rb[i].w, p);
        }
    }

    // emit one output row GR: numerator from window row SL, denominators d0..d3
    #define EMITROW(GR, SL) { \
        float* orw_ = oplane + (GR) * Ww; \
        v2f e0_ = {fmaf(wc * win[SL][2], d0, bc), fmaf(wc * win[SL][3], d1, bc)}; \
        v2f e1_ = {fmaf(wc * win[SL][4], d2, bc), fmaf(wc * win[SL][5], d3, bc)}; \
        __builtin_nontemporal_store(e0_, (v2f*)(orw_ + col0 + 2)); \
        __builtin_nontemporal_store(e1_, (v2f*)(orw_ + col0 + 4)); \
        if (g == 0) { \
            v2f eL_ = {fmaf(wc * win[SL][0], d0, bc), fmaf(wc * win[SL][1], d0, bc)}; \
            __builtin_nontemporal_store(eL_, (v2f*)(orw_)); } \
        if (g == 26) { \
            v2f eR_ = {fmaf(wc * win[SL][6], d3, bc), fmaf(wc * win[SL][7], d3, bc)}; \
            __builtin_nontemporal_store(eR_, (v2f*)(orw_ + 110)); } }

    #define EDGEEMITS() { \
        if (k == 0 && cb == 2)       { EMITROW(0, 0)   EMITROW(1, 1) } \
        if (k == 2 && cb == 107)     { EMITROW(110, 5) EMITROW(111, 6) } }

    if (uni) {
        // ---- box-filter fast path: conv = kw[0] * boxsum ----
        const float k0 = kw[0];
        float vs[8];   // vertical column sums over 5-row window
        #pragma unroll
        for (int tt = 0; tt < 8; ++tt)
            vs[tt] = ((win[0][tt] + win[1][tt]) + (win[2][tt] + win[3][tt]))
                     + win[4][tt];

        #pragma unroll
        for (int k = 0; k < RPS; ++k) {
            const float h0 = ((vs[0] + vs[1]) + (vs[2] + vs[3])) + vs[4];
            const float h1 = h0 - vs[0] + vs[5];
            const float h2 = h1 - vs[1] + vs[6];
            const float h3 = h2 - vs[2] + vs[7];

            const float d0 = __builtin_amdgcn_rcpf(fmaf(k0, h0, sp));
            const float d1 = __builtin_amdgcn_rcpf(fmaf(k0, h1, sp));
            const float d2 = __builtin_amdgcn_rcpf(fmaf(k0, h2, sp));
            const float d3 = __builtin_amdgcn_rcpf(fmaf(k0, h3, sp));

            EMITROW(cb + k, k + 2)
            EDGEEMITS()

            if (k < RPS - 1) {
                #pragma unroll
                for (int tt = 0; tt < 8; ++tt)
                    vs[tt] += win[k + 5][tt] - win[k][tt];
            }
        }
    } else {
        // ---- general 25-tap path ----
        #pragma unroll
        for (int k = 0; k < RPS; ++k) {
            float S0 = 0.f, S1 = 0.f, S2 = 0.f, S3 = 0.f;
            #pragma unroll
            for (int dy = 0; dy < 5; ++dy) {
                #pragma unroll
                for (int dx = 0; dx < 5; ++dx) {
                    const float kv = kw[dy * 5 + dx];
                    S0 = fmaf(kv, win[k + dy][dx + 0], S0);
                    S1 = fmaf(kv, win[k + dy][dx + 1], S1);
                    S2 = fmaf(kv, win[k + dy][dx + 2], S2);
                    S3 = fmaf(kv, win[k + dy][dx + 3], S3);
                }
            }

            const float d0 = __builtin_amdgcn_rcpf(sp + S0);
            const float d1 = __builtin_amdgcn_rcpf(sp + S1);
            const float d2 = __builtin_amdgcn_rcpf(sp + S2);
            const float d3 = __builtin_amdgcn_rcpf(sp + S3);

            EMITROW(cb + k, k + 2)
            EDGEEMITS()
        }
    }
    #undef EMITROW
    #undef EDGEEMITS
}

extern "C" void kernel_launch(void* const* d_in, const int* in_sizes, int n_in,
                              void* d_out, int out_size, void* d_ws, size_t ws_size,
                              hipStream_t stream) {
    const float* x          = (const float*)d_in[0];
    const float* sigma      = (const float*)d_in[1];
    const float* pow_p      = (const float*)d_in[2];
    const float* sum_kernel = (const float*)d_in[3];
    const float* weight     = (const float*)d_in[4];
    const float* bias       = (const float*)d_in[5];
    float* out = (float*)d_out;

    dim3 grid(RT, Cch / 2, 32);   // (row tiles, channel pairs, B)
    dim3 block(256);
    bionorm_kernel<<<grid, block, 0, stream>>>(x, sigma, pow_p, sum_kernel,
                                               weight, bias, out);
}

// Round 6
// 195.709 us; speedup vs baseline: 1.0201x; 1.0001x over previous
//
#include <hip/hip_runtime.h>

// BioNorm: out = w * x^p / (sigma^p + depthwise_conv5x5(x^p, edge-pad)) + b
// B=32, C=64, H=W=112, K=5, fp32.
//
// V6: plane-per-block, shuffle-based horizontal halo, single-load-per-element.
//  R5 post-mortem: (a) NT float2 stores amplified HBM writes +20% (partial
//  64B lines); (b) occupancy pinned ~30% because blocks are short-lived;
//  (c) 4.7x read amplification (450MB cache reads) with ~10 waves/CU ->
//  latency-bound, both pipes <35%.
//  - Block = one (b,c) plane, 256 thr. 8 half-waves x 14-row bands = 112 rows.
//    2048 blocks = exactly 8/CU: whole grid resident, zero dispatch pressure.
//  - Lane li (0..27 of 32) owns cols [4li,4li+3] for its whole band; each
//    input row loaded ONCE as an aligned float4 (lanes contiguous, 448B runs).
//    Horizontal conv halo via 4 __shfl of the vertical column sums (box path)
//    or of x^p (general path) -- no overlapped loads. Read volume 451->135MB.
//  - Depth-2 load prefetch + 5-slot x^p ring + rolling vertical sums; loop
//    fully unrolled (static ring indices, no scratch).
//  - NT stores now lane-contiguous float4 -> full 64B lines, no write amp.
//  - Edge-pad semantics: out rows/cols {0,1,110,111} use clamped-CENTER
//    denominator (row band 0/7 emit extra rows; col clamp via h/S selects).

#define Cch 64
#define Hh 112
#define Ww 112

typedef float v4f __attribute__((ext_vector_type(4)));

__global__ __launch_bounds__(256) void bionorm_kernel(
    const float* __restrict__ x, const float* __restrict__ sigma,
    const float* __restrict__ pow_p, const float* __restrict__ sum_kernel,
    const float* __restrict__ weight, const float* __restrict__ bias,
    float* __restrict__ out)
{
    const int c    = blockIdx.x;
    const int b    = blockIdx.y;
    const int tid  = threadIdx.x;
    const int wid  = tid >> 6;
    const int lane = tid & 63;
    const int half = lane >> 5;
    const int li   = lane & 31;
    if (li >= 28) return;                    // 28 active lanes per half

    const int hb     = wid * 2 + half;       // half-band 0..7 (rows 14hb..14hb+13)
    const int cstart = (hb == 0) ? 2 : 14 * hb;          // first center row
    const int ncent  = (hb == 0 || hb == 7) ? 12 : 14;   // centers this band
    const int col0   = 4 * li;
    const bool L0 = (li == 0), L27 = (li == 27);
    const int laneL = lane - 1, laneR = lane + 1;

    // per-channel params (wave-uniform -> scalar)
    const float p  = pow_p[c];
    const float sg = sigma[c];
    const float wc = weight[c];
    const float bc = bias[c];
    const bool  p2 = (p == 2.0f);
    const float sp = p2 ? sg * sg : __powf(sg, p);

    const float* kp = sum_kernel + c * 25;
    float kw[25];
    #pragma unroll
    for (int j = 0; j < 25; ++j) kw[j] = kp[j];
    bool uni = true;
    #pragma unroll
    for (int j = 1; j < 25; ++j) uni = uni && (kw[j] == kw[0]);

    const float* xplane = x + ((size_t)(b * Cch + c)) * (Hh * Ww);
    float* oplane = out + ((size_t)(b * Cch + c)) * (Hh * Ww);

    // ---- issue prologue loads back-to-back: rows cstart-2 .. cstart+3 ----
    #define LOADR(GR) (*(const v4f*)(xplane + (GR) * Ww + col0))
    const v4f r0 = LOADR(cstart - 2);
    const v4f r1 = LOADR(cstart - 1);
    const v4f r2 = LOADR(cstart    );
    const v4f r3 = LOADR(cstart + 1);
    v4f pend[2];
    pend[0] = LOADR(cstart + 2);
    pend[1] = LOADR(cstart + 3);

    #define P4(V) (p2 ? (V) * (V) \
        : (v4f){__powf((V).x, p), __powf((V).y, p), __powf((V).z, p), __powf((V).w, p)})

    #define NTST(PTR, VAL) __builtin_nontemporal_store((VAL), (v4f*)(PTR))

    if (uni) {
        // ================= box-filter path: conv = k0 * boxsum =================
        const float k0 = kw[0];
        v4f xp[5];
        xp[0] = P4(r0); xp[1] = P4(r1); xp[2] = P4(r2); xp[3] = P4(r3);
        v4f vs = xp[0] + xp[1] + xp[2] + xp[3];   // vertical col sums (4 rows)

        #pragma unroll
        for (int k = 0; k < 14; ++k) {
            // consume prefetched row cstart+2+k -> slot (k+4)%5; add to vs
            const v4f nw = P4(pend[k & 1]);
            xp[(k + 4) % 5] = nw;
            vs += nw;
            // reissue: row cstart+4+k (used at iter k+2), clamped dup-safe
            int lr = cstart + 4 + k; if (lr > 111) lr = 111;
            pend[k & 1] = LOADR(lr);

            // horizontal box from vs + neighbor col sums (4 shuffles)
            const float vs0 = vs.x, vs1 = vs.y, vs2 = vs.z, vs3 = vs.w;
            const float vL2 = __shfl(vs2, laneL, 64);  // col 4li-2
            const float vL3 = __shfl(vs3, laneL, 64);  // col 4li-1
            const float vR0 = __shfl(vs0, laneR, 64);  // col 4li+4
            const float vR1 = __shfl(vs1, laneR, 64);  // col 4li+5
            const float a  = vs0 + vs1 + vs2;
            float h0 = vL2 + vL3 + a;                  // center col 4li
            float h1 = vL3 + a + vs3;
            float h2 = a + vs3 + vR0;
            float h3 = (vs1 + vs2 + vs3) + (vR0 + vR1);
            if (L0)  { h0 = h2; h1 = h2; }             // cols 0,1 -> center 2
            if (L27) { h2 = h1; h3 = h1; }             // cols 110,111 -> center 109

            const float d0 = __builtin_amdgcn_rcpf(fmaf(k0, h0, sp));
            const float d1 = __builtin_amdgcn_rcpf(fmaf(k0, h1, sp));
            const float d2 = __builtin_amdgcn_rcpf(fmaf(k0, h2, sp));
            const float d3 = __builtin_amdgcn_rcpf(fmaf(k0, h3, sp));

            const v4f nm = xp[(k + 2) % 5];            // x^p of center row
            const v4f o  = {fmaf(wc * nm.x, d0, bc), fmaf(wc * nm.y, d1, bc),
                            fmaf(wc * nm.z, d2, bc), fmaf(wc * nm.w, d3, bc)};
            if (k < ncent)
                NTST(oplane + (cstart + k) * Ww + col0, o);

            if (hb == 0 && k == 0) {                   // pad rows 0,1 (den of row 2)
                const v4f nA = xp[0], nB = xp[1];
                NTST(oplane + 0 * Ww + col0,
                     ((v4f){fmaf(wc*nA.x,d0,bc), fmaf(wc*nA.y,d1,bc),
                            fmaf(wc*nA.z,d2,bc), fmaf(wc*nA.w,d3,bc)}));
                NTST(oplane + 1 * Ww + col0,
                     ((v4f){fmaf(wc*nB.x,d0,bc), fmaf(wc*nB.y,d1,bc),
                            fmaf(wc*nB.z,d2,bc), fmaf(wc*nB.w,d3,bc)}));
            }
            if (hb == 7 && k == 11) {                  // pad rows 110,111 (den of 109)
                const v4f nA = xp[4];                  // row 110
                const v4f nB = xp[0];                  // row 111
                NTST(oplane + 110 * Ww + col0,
                     ((v4f){fmaf(wc*nA.x,d0,bc), fmaf(wc*nA.y,d1,bc),
                            fmaf(wc*nA.z,d2,bc), fmaf(wc*nA.w,d3,bc)}));
                NTST(oplane + 111 * Ww + col0,
                     ((v4f){fmaf(wc*nB.x,d0,bc), fmaf(wc*nB.y,d1,bc),
                            fmaf(wc*nB.z,d2,bc), fmaf(wc*nB.w,d3,bc)}));
            }

            vs -= xp[k % 5];                           // drop leaving row
        }
    } else {
        // ================= general 25-tap path =================
        // ring row = 8 cols: [4li-2 .. 4li+5]; halo via 4 shuffles at convert
        float va[5][8];
        #define CVT8G(SL, RV) { \
            const v4f t_ = P4(RV); \
            va[SL][2] = t_.x; va[SL][3] = t_.y; va[SL][4] = t_.z; va[SL][5] = t_.w; \
            va[SL][0] = __shfl(t_.z, laneL, 64); \
            va[SL][1] = __shfl(t_.w, laneL, 64); \
            va[SL][6] = __shfl(t_.x, laneR, 64); \
            va[SL][7] = __shfl(t_.y, laneR, 64); }

        CVT8G(0, r0) CVT8G(1, r1) CVT8G(2, r2) CVT8G(3, r3)

        #pragma unroll
        for (int k = 0; k < 14; ++k) {
            CVT8G((k + 4) % 5, pend[k & 1])
            int lr = cstart + 4 + k; if (lr > 111) lr = 111;
            pend[k & 1] = LOADR(lr);

            float S0 = 0.f, S1 = 0.f, S2 = 0.f, S3 = 0.f;
            #pragma unroll
            for (int dy = 0; dy < 5; ++dy) {
                const int sl = (k + dy) % 5;
                #pragma unroll
                for (int dx = 0; dx < 5; ++dx) {
                    const float kv = kw[dy * 5 + dx];
                    S0 = fmaf(kv, va[sl][dx + 0], S0);
                    S1 = fmaf(kv, va[sl][dx + 1], S1);
                    S2 = fmaf(kv, va[sl][dx + 2], S2);
                    S3 = fmaf(kv, va[sl][dx + 3], S3);
                }
            }
            if (L0)  { S0 = S2; S1 = S2; }
            if (L27) { S2 = S1; S3 = S1; }

            const float d0 = __builtin_amdgcn_rcpf(sp + S0);
            const float d1 = __builtin_amdgcn_rcpf(sp + S1);
            const float d2 = __builtin_amdgcn_rcpf(sp + S2);
            const float d3 = __builtin_amdgcn_rcpf(sp + S3);

            #define NUM4(SL) ((v4f){va[SL][2], va[SL][3], va[SL][4], va[SL][5]})
            const v4f nm = NUM4((k + 2) % 5);
            const v4f o  = {fmaf(wc * nm.x, d0, bc), fmaf(wc * nm.y, d1, bc),
                            fmaf(wc * nm.z, d2, bc), fmaf(wc * nm.w, d3, bc)};
            if (k < ncent)
                NTST(oplane + (cstart + k) * Ww + col0, o);

            if (hb == 0 && k == 0) {
                const v4f nA = NUM4(0), nB = NUM4(1);
                NTST(oplane + 0 * Ww + col0,
                     ((v4f){fmaf(wc*nA.x,d0,bc), fmaf(wc*nA.y,d1,bc),
                            fmaf(wc*nA.z,d2,bc), fmaf(wc*nA.w,d3,bc)}));
                NTST(oplane + 1 * Ww + col0,
                     ((v4f){fmaf(wc*nB.x,d0,bc), fmaf(wc*nB.y,d1,bc),
                            fmaf(wc*nB.z,d2,bc), fmaf(wc*nB.w,d3,bc)}));
            }
            if (hb == 7 && k == 11) {
                const v4f nA = NUM4(4);   // row 110
                const v4f nB = NUM4(0);   // row 111
                NTST(oplane + 110 * Ww + col0,
                     ((v4f){fmaf(wc*nA.x,d0,bc), fmaf(wc*nA.y,d1,bc),
                            fmaf(wc*nA.z,d2,bc), fmaf(wc*nA.w,d3,bc)}));
                NTST(oplane + 111 * Ww + col0,
                     ((v4f){fmaf(wc*nB.x,d0,bc), fmaf(wc*nB.y,d1,bc),
                            fmaf(wc*nB.z,d2,bc), fmaf(wc*nB.w,d3,bc)}));
            }
            #undef NUM4
        }
        #undef CVT8G
    }
    #undef P4
    #undef NTST
    #undef LOADR
}

extern "C" void kernel_launch(void* const* d_in, const int* in_sizes, int n_in,
                              void* d_out, int out_size, void* d_ws, size_t ws_size,
                              hipStream_t stream) {
    const float* x          = (const float*)d_in[0];
    const float* sigma      = (const float*)d_in[1];
    const float* pow_p      = (const float*)d_in[2];
    const float* sum_kernel = (const float*)d_in[3];
    const float* weight     = (const float*)d_in[4];
    const float* bias       = (const float*)d_in[5];
    float* out = (float*)d_out;

    dim3 grid(Cch, 32);   // one block per (c, b) plane; 2048 blocks = 8/CU
    dim3 block(256);
    bionorm_kernel<<<grid, block, 0, stream>>>(x, sigma, pow_p, sum_kernel,
                                               weight, bias, out);
}

// Round 8
// 192.062 us; speedup vs baseline: 1.0395x; 1.0190x over previous
//
#include <hip/hip_runtime.h>

// BioNorm: out = w * x^p / (sigma^p + depthwise_conv5x5(x^p, edge-pad)) + b
// B=32, C=64, H=W=112, K=5, fp32.
//
// V7 (resubmit; R7 bench was an infra failure "container failed twice").
//  R6 post-mortem: four LDS-free structures (R2/R3/R5/R6) all pinned at
//  68-73us with occupancy 30-36% and both pipes idle -> latency wall from
//  low residency, not a BW wall (copy ubench does 6.3 TB/s at ~100% occ).
//  The only high-occupancy config measured was R0 (72.5%: 8192 blocks x
//  256thr x 14.85KB LDS); its cost was 27.6M LDS-conflict cycles (51% of
//  runtime) from scalar b32 reads -- a solved problem.
//  = R0 geometry (occupancy) + R1 center-anchored b128 reads (0 conflicts)
//    + R3 box fast path (halved VALU) + cached stores (no write amp):
//  - Block = (rt, c, b), 28 output rows, stages 32 rows x 112 of x^p in LDS
//    (stride 116 floats; 14.85 KB -> 8+ blocks/CU by LDS, VGPR ~56).
//  - Compute items: 28 rows x 27 col-groups; group g covers window cols
//    [4g,4g+8) -> 2x ds_read_b128 per row, 16B-aligned, 32B lane stride =
//    conflict-free (8 lanes/phase span all 32 banks). Centers 4g+2..4g+5.
//  - Box path (all-25-taps-equal, wave-uniform runtime check): vertical
//    col-sums v[8] + incremental horizontal box; general 25-tap path kept
//    (streamed rows, no 5x8 live window).
//  - Edge rows/cols: denominator of clamped CENTER (cr=clamp(r,2,109));
//    numerator = real pixel row (slot lr+2; re-read only when r!=cr).
//    g==0 emits cols 0,1 (den d0); g==26 emits cols 110,111 (den d3).

#define Cch 64
#define Hh 112
#define Ww 112
#define TH 28          // output rows per tile (112 = 4*28)
#define LROWS 32       // staged rows
#define ST 116         // LDS row stride in floats

__global__ __launch_bounds__(256) void bionorm_kernel(
    const float* __restrict__ x, const float* __restrict__ sigma,
    const float* __restrict__ pow_p, const float* __restrict__ sum_kernel,
    const float* __restrict__ weight, const float* __restrict__ bias,
    float* __restrict__ out)
{
    __shared__ float lds[LROWS * ST];

    const int rt  = blockIdx.x;   // row tile 0..3
    const int c   = blockIdx.y;
    const int b   = blockIdx.z;
    const int tid = threadIdx.x;
    const int r0  = rt * TH;

    // per-channel params (wave-uniform)
    const float p  = pow_p[c];
    const float sg = sigma[c];
    const float wc = weight[c];
    const float bc = bias[c];
    const bool  p2 = (p == 2.0f);
    const float sp = p2 ? sg * sg : __powf(sg, p);

    float kw[25];
    const float* kp = sum_kernel + c * 25;
    #pragma unroll
    for (int j = 0; j < 25; ++j) kw[j] = kp[j];
    bool uni = true;
    #pragma unroll
    for (int j = 1; j < 25; ++j) uni = uni && (kw[j] == kw[0]);

    const float* xplane = x + ((size_t)(b * Cch + c)) * (Hh * Ww);

    // ---- stage x^p tile: 32 rows x 28 float4 (edge rows clamp-replicated) ----
    for (int i = tid; i < LROWS * 28; i += 256) {
        int s = i / 28, q = i - s * 28;
        int g = r0 - 2 + s;
        g = g < 0 ? 0 : (g > 111 ? 111 : g);
        const float4 v = *(const float4*)(xplane + g * Ww + q * 4);
        float4 xp;
        if (p2) {
            xp.x = v.x * v.x; xp.y = v.y * v.y;
            xp.z = v.z * v.z; xp.w = v.w * v.w;
        } else {
            xp.x = __powf(v.x, p); xp.y = __powf(v.y, p);
            xp.z = __powf(v.z, p); xp.w = __powf(v.w, p);
        }
        *(float4*)(&lds[s * ST + q * 4]) = xp;
    }
    __syncthreads();

    float* oplane = out + ((size_t)(b * Cch + c)) * (Hh * Ww);

    // emit the 4 centers + edge cols for one output row r
    #define STOREOUT() { \
        float* orw_ = oplane + r * Ww; \
        *(float2*)(orw_ + base + 2) = make_float2(fmaf(wc * n2, d0, bc), \
                                                  fmaf(wc * n3, d1, bc)); \
        *(float2*)(orw_ + base + 4) = make_float2(fmaf(wc * n4, d2, bc), \
                                                  fmaf(wc * n5, d3, bc)); \
        if (g == 0)  *(float2*)(orw_)       = make_float2(fmaf(wc * n0, d0, bc), \
                                                          fmaf(wc * n1, d0, bc)); \
        if (g == 26) *(float2*)(orw_ + 110) = make_float2(fmaf(wc * n6, d3, bc), \
                                                          fmaf(wc * n7, d3, bc)); }

    #define RENUM() { \
        if (r != cr) { /* rows 0,1,110,111: numerator = real row */ \
            const float* nrw_ = &lds[(lr + 2) * ST + base]; \
            const float4 na_ = *(const float4*)(nrw_); \
            const float4 nb_ = *(const float4*)(nrw_ + 4); \
            n0 = na_.x; n1 = na_.y; n2 = na_.z; n3 = na_.w; \
            n4 = nb_.x; n5 = nb_.y; n6 = nb_.z; n7 = nb_.w; } }

    if (uni) {
        // ---- box-filter path: conv = kw[0] * boxsum ----
        const float k0 = kw[0];
        for (int i = tid; i < TH * 27; i += 256) {
            const int lr = i / 27, g = i - lr * 27;
            const int r    = r0 + lr;
            const int cr   = r < 2 ? 2 : (r > 109 ? 109 : r);
            const int sRow = cr - r0;     // slot of global row cr-2
            const int base = 4 * g;       // window cols [4g, 4g+8)

            float v0 = 0.f, v1 = 0.f, v2 = 0.f, v3 = 0.f;
            float v4 = 0.f, v5 = 0.f, v6 = 0.f, v7 = 0.f;
            float n0, n1, n2, n3, n4, n5, n6, n7;
            #pragma unroll
            for (int dy = 0; dy < 5; ++dy) {
                const float* row = &lds[(sRow + dy) * ST + base];
                const float4 a = *(const float4*)(row);
                const float4 e = *(const float4*)(row + 4);
                v0 += a.x; v1 += a.y; v2 += a.z; v3 += a.w;
                v4 += e.x; v5 += e.y; v6 += e.z; v7 += e.w;
                if (dy == 2) {
                    n0 = a.x; n1 = a.y; n2 = a.z; n3 = a.w;
                    n4 = e.x; n5 = e.y; n6 = e.z; n7 = e.w;
                }
            }
            RENUM()

            const float h0 = ((v0 + v1) + (v2 + v3)) + v4;
            const float h1 = h0 - v0 + v5;
            const float h2 = h1 - v1 + v6;
            const float h3 = h2 - v2 + v7;

            const float d0 = __builtin_amdgcn_rcpf(fmaf(k0, h0, sp));
            const float d1 = __builtin_amdgcn_rcpf(fmaf(k0, h1, sp));
            const float d2 = __builtin_amdgcn_rcpf(fmaf(k0, h2, sp));
            const float d3 = __builtin_amdgcn_rcpf(fmaf(k0, h3, sp));

            STOREOUT()
        }
    } else {
        // ---- general 25-tap path (rows streamed, no live 5x8 window) ----
        for (int i = tid; i < TH * 27; i += 256) {
            const int lr = i / 27, g = i - lr * 27;
            const int r    = r0 + lr;
            const int cr   = r < 2 ? 2 : (r > 109 ? 109 : r);
            const int sRow = cr - r0;
            const int base = 4 * g;

            float S0 = 0.f, S1 = 0.f, S2 = 0.f, S3 = 0.f;
            float n0, n1, n2, n3, n4, n5, n6, n7;
            #pragma unroll
            for (int dy = 0; dy < 5; ++dy) {
                const float* row = &lds[(sRow + dy) * ST + base];
                const float4 a = *(const float4*)(row);
                const float4 e = *(const float4*)(row + 4);
                const float rv[8] = {a.x, a.y, a.z, a.w, e.x, e.y, e.z, e.w};
                #pragma unroll
                for (int dx = 0; dx < 5; ++dx) {
                    const float kv = kw[dy * 5 + dx];
                    S0 = fmaf(kv, rv[dx + 0], S0);
                    S1 = fmaf(kv, rv[dx + 1], S1);
                    S2 = fmaf(kv, rv[dx + 2], S2);
                    S3 = fmaf(kv, rv[dx + 3], S3);
                }
                if (dy == 2) {
                    n0 = rv[0]; n1 = rv[1]; n2 = rv[2]; n3 = rv[3];
                    n4 = rv[4]; n5 = rv[5]; n6 = rv[6]; n7 = rv[7];
                }
            }
            RENUM()

            const float d0 = __builtin_amdgcn_rcpf(sp + S0);
            const float d1 = __builtin_amdgcn_rcpf(sp + S1);
            const float d2 = __builtin_amdgcn_rcpf(sp + S2);
            const float d3 = __builtin_amdgcn_rcpf(sp + S3);

            STOREOUT()
        }
    }
    #undef STOREOUT
    #undef RENUM
}

extern "C" void kernel_launch(void* const* d_in, const int* in_sizes, int n_in,
                              void* d_out, int out_size, void* d_ws, size_t ws_size,
                              hipStream_t stream) {
    const float* x          = (const float*)d_in[0];
    const float* sigma      = (const float*)d_in[1];
    const float* pow_p      = (const float*)d_in[2];
    const float* sum_kernel = (const float*)d_in[3];
    const float* weight     = (const float*)d_in[4];
    const float* bias       = (const float*)d_in[5];
    float* out = (float*)d_out;

    dim3 grid(4, Cch, 32);   // (row tiles, C, B) = 8192 blocks
    dim3 block(256);
    bionorm_kernel<<<grid, block, 0, stream>>>(x, sigma, pow_p, sum_kernel,
                                               weight, bias, out);
}